// Round 4
// baseline (207.032 us; speedup 1.0000x reference)
//
#include <hip/hip_runtime.h>

#define H   384
#define W   384
#define HW  (H*W)
#define BLK 192   // 3 waves: one per output color channel

// Broadcast a wave-uniform float into an SGPR.
__device__ __forceinline__ float uread(float x) {
    return __int_as_float(__builtin_amdgcn_readfirstlane(__float_as_int(x)));
}

// 3-tap weights for one axis: sample at pos+shift lands in [pos-1, pos+1];
// fold the floor offset (0/1) into the taps so the hot loop is pure FMA.
#define MKTAP(g_, pos_, t0, t1, t2)                                       \
    { float x_  = fminf(fmaxf(((g_) + 1.0f) * 0.5f * 383.0f, 0.0f), 383.0f); \
      float x0f = floorf(x_);                                             \
      float wx_ = x_ - x0f;                                               \
      int   dX  = (int)x0f - (pos_) + 1;                                  \
      t0 = dX ? 0.0f       : 1.0f - wx_;                                  \
      t1 = dX ? 1.0f - wx_ : wx_;                                         \
      t2 = dX ? wx_        : 0.0f; }

// One thread per (pixel, color). Coordinates mirror make_filters (f64) then
// _warp (f32) — validated R2/R3. New in R4: rank-factorized bilinear form
//   out[ak,al] = ay[ak]^T * ( sum_r (h0*v1) h2^T ) * ay[4-ak]
// so the 25-view evaluation happens once, not per rank.
__global__ __launch_bounds__(BLK, 4) void multilayer_m(
    const float* __restrict__ layers, float* __restrict__ out)
{
    const int lane = threadIdx.x & 63;
    const int c    = threadIdx.x >> 6;                         // wave-uniform
    const int cu   = __builtin_amdgcn_readfirstlane(c);        // → SGPR
    const int b    = blockIdx.x;
    const int i    = b / 6;                                    // row
    const int j    = (b - i * 6) * 64 + lane;                  // col

    const double stepd = 2.0 / 383.0;            // np.linspace(-1,1,384) step
    const double flowx = (double)j * stepd - 1.0;
    const double flowy = (double)i * stepd - 1.0;

    // ---- x-axis tap tables (per-lane, VGPR) ----
    float ax0[5][3], ax1[3];
#pragma unroll
    for (int v = 0; v < 5; ++v) {
        // layer c=-1 shift: d = ((-1/384)*(v-2)) * (-1), f64 like make_filters
        const double d = ((-1.0 / 384.0) * (double)(v - 2)) * (-1.0);
        const float  g = (float)(d + flowx);
        MKTAP(g, j, ax0[v][0], ax0[v][1], ax0[v][2])
    }
    { const float g = (float)flowx; MKTAP(g, j, ax1[0], ax1[1], ax1[2]) }

    // ---- y-axis tap tables (block-uniform → SGPR via readfirstlane) ----
    float ay0[5][3], ay1[3];
#pragma unroll
    for (int v = 0; v < 5; ++v) {
        const double d = ((-1.0 / 384.0) * (double)(v - 2)) * (-1.0);
        const float  g = (float)(d + flowy);
        float t0, t1, t2;
        MKTAP(g, i, t0, t1, t2)
        ay0[v][0] = uread(t0); ay0[v][1] = uread(t1); ay0[v][2] = uread(t2);
    }
    {
        const float g = (float)flowy;
        float t0, t1, t2;
        MKTAP(g, i, t0, t1, t2)
        // fold the 0.25 rank-mean into the middle-layer y-taps
        ay1[0] = uread(0.25f * t0); ay1[1] = uread(0.25f * t1); ay1[2] = uread(0.25f * t2);
    }

    // ---- 3x3 neighborhood byte offsets (clamped), 32-bit voffsets ----
    const int jm = max(j - 1, 0), jp = min(j + 1, W - 1);
    const int im = max(i - 1, 0), ip = min(i + 1, H - 1);
    const int r0 = im * W, r1 = i * W, r2 = ip * W;
    const int voff[9] = { (r0 + jm) * 4, (r0 + j) * 4, (r0 + jp) * 4,
                          (r1 + jm) * 4, (r1 + j) * 4, (r1 + jp) * 4,
                          (r2 + jm) * 4, (r2 + j) * 4, (r2 + jp) * 4 };
    const char* base = (const char*)layers;

    float M[5][3][3] = {};   // M[al][p][q], accumulated across ranks

#pragma unroll 1
    for (int r = 0; r < 4; ++r) {
        const int ch = r * 3 + cu;                       // scalar
        const char* p0 = base + (size_t)ch * (HW * 4);   // layer c=-1 (scalar base)
        const char* p1 = p0 + (size_t)12 * (HW * 4);     // layer c= 0
        const char* p2 = p0 + (size_t)24 * (HW * 4);     // layer c=+1

        float n0[9], n1[9], n2[9];
#pragma unroll
        for (int t = 0; t < 9; ++t) {
            n0[t] = *(const float*)(p0 + voff[t]);
            n1[t] = *(const float*)(p1 + voff[t]);
            n2[t] = *(const float*)(p2 + voff[t]);
        }

        // middle layer: single sample shared by all views, pre-scaled by 0.25
        const float hy0 = ax1[0] * n1[0] + ax1[1] * n1[1] + ax1[2] * n1[2];
        const float hy1 = ax1[0] * n1[3] + ax1[1] * n1[4] + ax1[2] * n1[5];
        const float hy2 = ax1[0] * n1[6] + ax1[1] * n1[7] + ax1[2] * n1[8];
        const float v1  = ay1[0] * hy0 + ay1[1] * hy1 + ay1[2] * hy2;

#pragma unroll
        for (int al = 0; al < 5; ++al) {
            float h0[3], h2[3];
#pragma unroll
            for (int dy = 0; dy < 3; ++dy) {
                h0[dy] = (ax0[al][0]     * n0[dy*3] + ax0[al][1]     * n0[dy*3+1] + ax0[al][2]     * n0[dy*3+2]) * v1;
                h2[dy] =  ax0[4-al][0]   * n2[dy*3] + ax0[4-al][1]   * n2[dy*3+1] + ax0[4-al][2]   * n2[dy*3+2];
            }
#pragma unroll
            for (int p = 0; p < 3; ++p)
#pragma unroll
                for (int q = 0; q < 3; ++q)
                    M[al][p][q] += h0[p] * h2[q];
        }
    }

    // ---- 25 quadratic forms, one store each: out[a][c][i][j], a = ak*5+al ----
    const size_t ob = (size_t)cu * HW + (size_t)i * W + j;
#pragma unroll
    for (int ak = 0; ak < 5; ++ak) {
        const float q0 = ay0[4 - ak][0], q1 = ay0[4 - ak][1], q2 = ay0[4 - ak][2];
        const float l0 = ay0[ak][0],     l1 = ay0[ak][1],     l2 = ay0[ak][2];
#pragma unroll
        for (int al = 0; al < 5; ++al) {
            const float t0 = M[al][0][0] * q0 + M[al][0][1] * q1 + M[al][0][2] * q2;
            const float t1 = M[al][1][0] * q0 + M[al][1][1] * q1 + M[al][1][2] * q2;
            const float t2 = M[al][2][0] * q0 + M[al][2][1] * q1 + M[al][2][2] * q2;
            const float s  = l0 * t0 + l1 * t1 + l2 * t2;
            out[(size_t)(ak * 5 + al) * (3 * HW) + ob] = s;
        }
    }
}

extern "C" void kernel_launch(void* const* d_in, const int* in_sizes, int n_in,
                              void* d_out, int out_size, void* d_ws, size_t ws_size,
                              hipStream_t stream) {
    const float* layers = (const float*)d_in[0];   // [1,3,4,3,384,384] f32
    // d_in[1] (filters) unused: coordinates recomputed analytically (validated R2/R3).
    float* out = (float*)d_out;                    // [1,25,3,384,384] f32

    const int n_blocks = HW / 64;                  // 2304 blocks of 192 threads
    multilayer_m<<<n_blocks, BLK, 0, stream>>>(layers, out);
}

// Round 5
// 201.155 us; speedup vs baseline: 1.0292x; 1.0292x over previous
//
#include <hip/hip_runtime.h>

#define H   384
#define W   384
#define HW  (H*W)
#define BLK 192   // 3 waves: one per output color channel

// Broadcast a wave-uniform float into an SGPR.
__device__ __forceinline__ float uread(float x) {
    return __int_as_float(__builtin_amdgcn_readfirstlane(__float_as_int(x)));
}

// 3-tap weights for one axis: sample at pos+shift lands in [pos-1, pos+1];
// fold the floor offset (0/1) into the taps so the hot loop is pure FMA.
#define MKTAP(g_, pos_, t0, t1, t2)                                       \
    { float x_  = fminf(fmaxf(((g_) + 1.0f) * 0.5f * 383.0f, 0.0f), 383.0f); \
      float x0f = floorf(x_);                                             \
      float wx_ = x_ - x0f;                                               \
      int   dX  = (int)x0f - (pos_) + 1;                                  \
      t0 = dX ? 0.0f       : 1.0f - wx_;                                  \
      t1 = dX ? 1.0f - wx_ : wx_;                                         \
      t2 = dX ? wx_        : 0.0f; }

// One thread per (pixel, color). Coordinates mirror make_filters (f64) then
// _warp (f32) — validated R2-R4. Rank-factorized bilinear form:
//   out[ak,al] = ay[ak]^T * ( sum_r (h0*v1) h2^T ) * ay[4-ak]
// R5: XCD-aware row-band swizzle (each XCD's L2 holds a 2.8 MB band instead of
// thrashing the whole 21 MB image: R4 showed 147 MB FETCH = ~8x21 MB) and
// non-temporal output stores so the 44 MB stream doesn't evict the band.
__global__ __launch_bounds__(BLK, 4) void multilayer_m(
    const float* __restrict__ layers, float* __restrict__ out)
{
    const int lane = threadIdx.x & 63;
    const int c    = threadIdx.x >> 6;                         // wave-uniform
    const int cu   = __builtin_amdgcn_readfirstlane(c);        // → SGPR
    // XCD swizzle: consecutive blockIdx are dispatched round-robin across the
    // 8 XCDs; remap so XCD k gets the contiguous row band [48k, 48k+48).
    const int b    = (blockIdx.x & 7) * 288 + (blockIdx.x >> 3);
    const int i    = b / 6;                                    // row
    const int j    = (b - i * 6) * 64 + lane;                  // col

    const double stepd = 2.0 / 383.0;            // np.linspace(-1,1,384) step
    const double flowx = (double)j * stepd - 1.0;
    const double flowy = (double)i * stepd - 1.0;

    // ---- x-axis tap tables (per-lane, VGPR) ----
    float ax0[5][3], ax1[3];
#pragma unroll
    for (int v = 0; v < 5; ++v) {
        // layer c=-1 shift: d = ((-1/384)*(v-2)) * (-1), f64 like make_filters
        const double d = ((-1.0 / 384.0) * (double)(v - 2)) * (-1.0);
        const float  g = (float)(d + flowx);
        MKTAP(g, j, ax0[v][0], ax0[v][1], ax0[v][2])
    }
    { const float g = (float)flowx; MKTAP(g, j, ax1[0], ax1[1], ax1[2]) }

    // ---- y-axis tap tables (block-uniform → SGPR via readfirstlane) ----
    float ay0[5][3], ay1[3];
#pragma unroll
    for (int v = 0; v < 5; ++v) {
        const double d = ((-1.0 / 384.0) * (double)(v - 2)) * (-1.0);
        const float  g = (float)(d + flowy);
        float t0, t1, t2;
        MKTAP(g, i, t0, t1, t2)
        ay0[v][0] = uread(t0); ay0[v][1] = uread(t1); ay0[v][2] = uread(t2);
    }
    {
        const float g = (float)flowy;
        float t0, t1, t2;
        MKTAP(g, i, t0, t1, t2)
        // fold the 0.25 rank-mean into the middle-layer y-taps
        ay1[0] = uread(0.25f * t0); ay1[1] = uread(0.25f * t1); ay1[2] = uread(0.25f * t2);
    }

    // ---- 3x3 neighborhood byte offsets (clamped), 32-bit voffsets ----
    const int jm = max(j - 1, 0), jp = min(j + 1, W - 1);
    const int im = max(i - 1, 0), ip = min(i + 1, H - 1);
    const int r0 = im * W, r1 = i * W, r2 = ip * W;
    const int voff[9] = { (r0 + jm) * 4, (r0 + j) * 4, (r0 + jp) * 4,
                          (r1 + jm) * 4, (r1 + j) * 4, (r1 + jp) * 4,
                          (r2 + jm) * 4, (r2 + j) * 4, (r2 + jp) * 4 };
    const char* base = (const char*)layers;

    float M[5][3][3] = {};   // M[al][p][q], accumulated across ranks

#pragma unroll 1
    for (int r = 0; r < 4; ++r) {
        const int ch = r * 3 + cu;                       // scalar
        const char* p0 = base + (size_t)ch * (HW * 4);   // layer c=-1 (scalar base)
        const char* p1 = p0 + (size_t)12 * (HW * 4);     // layer c= 0
        const char* p2 = p0 + (size_t)24 * (HW * 4);     // layer c=+1

        float n0[9], n1[9], n2[9];
#pragma unroll
        for (int t = 0; t < 9; ++t) {
            n0[t] = *(const float*)(p0 + voff[t]);
            n1[t] = *(const float*)(p1 + voff[t]);
            n2[t] = *(const float*)(p2 + voff[t]);
        }

        // middle layer: single sample shared by all views, pre-scaled by 0.25
        const float hy0 = ax1[0] * n1[0] + ax1[1] * n1[1] + ax1[2] * n1[2];
        const float hy1 = ax1[0] * n1[3] + ax1[1] * n1[4] + ax1[2] * n1[5];
        const float hy2 = ax1[0] * n1[6] + ax1[1] * n1[7] + ax1[2] * n1[8];
        const float v1  = ay1[0] * hy0 + ay1[1] * hy1 + ay1[2] * hy2;

#pragma unroll
        for (int al = 0; al < 5; ++al) {
            float h0[3], h2[3];
#pragma unroll
            for (int dy = 0; dy < 3; ++dy) {
                h0[dy] = (ax0[al][0]     * n0[dy*3] + ax0[al][1]     * n0[dy*3+1] + ax0[al][2]     * n0[dy*3+2]) * v1;
                h2[dy] =  ax0[4-al][0]   * n2[dy*3] + ax0[4-al][1]   * n2[dy*3+1] + ax0[4-al][2]   * n2[dy*3+2];
            }
#pragma unroll
            for (int p = 0; p < 3; ++p)
#pragma unroll
                for (int q = 0; q < 3; ++q)
                    M[al][p][q] += h0[p] * h2[q];
        }
    }

    // ---- 25 quadratic forms, one NT store each: out[a][c][i][j], a = ak*5+al ----
    const size_t ob = (size_t)cu * HW + (size_t)i * W + j;
#pragma unroll
    for (int ak = 0; ak < 5; ++ak) {
        const float q0 = ay0[4 - ak][0], q1 = ay0[4 - ak][1], q2 = ay0[4 - ak][2];
        const float l0 = ay0[ak][0],     l1 = ay0[ak][1],     l2 = ay0[ak][2];
#pragma unroll
        for (int al = 0; al < 5; ++al) {
            const float t0 = M[al][0][0] * q0 + M[al][0][1] * q1 + M[al][0][2] * q2;
            const float t1 = M[al][1][0] * q0 + M[al][1][1] * q1 + M[al][1][2] * q2;
            const float t2 = M[al][2][0] * q0 + M[al][2][1] * q1 + M[al][2][2] * q2;
            const float s  = l0 * t0 + l1 * t1 + l2 * t2;
            __builtin_nontemporal_store(s, out + (size_t)(ak * 5 + al) * (3 * HW) + ob);
        }
    }
}

extern "C" void kernel_launch(void* const* d_in, const int* in_sizes, int n_in,
                              void* d_out, int out_size, void* d_ws, size_t ws_size,
                              hipStream_t stream) {
    const float* layers = (const float*)d_in[0];   // [1,3,4,3,384,384] f32
    // d_in[1] (filters) unused: coordinates recomputed analytically (validated R2-R4).
    float* out = (float*)d_out;                    // [1,25,3,384,384] f32

    const int n_blocks = HW / 64;                  // 2304 blocks of 192 threads
    multilayer_m<<<n_blocks, BLK, 0, stream>>>(layers, out);
}

// Round 6
// 150.820 us; speedup vs baseline: 1.3727x; 1.3337x over previous
//
#include <hip/hip_runtime.h>

#define H   384
#define W   384
#define HW  (H*W)
#define BLK 192   // 3 waves: one per output color channel

// Broadcast a wave-uniform float into an SGPR.
__device__ __forceinline__ float uread(float x) {
    return __int_as_float(__builtin_amdgcn_readfirstlane(__float_as_int(x)));
}

// 3-tap weights for one axis: the sample lands in [pos-1, pos+1]; fold the
// floor offset (0/1) into the taps so the hot loop is pure FMA.
#define MKTAP(g_, pos_, t0, t1, t2)                                       \
    { float x_  = fminf(fmaxf(((g_) + 1.0f) * 0.5f * 383.0f, 0.0f), 383.0f); \
      float x0f = floorf(x_);                                             \
      float wx_ = x_ - x0f;                                               \
      int   dX  = (int)x0f - (pos_) + 1;                                  \
      t0 = dX ? 0.0f       : 1.0f - wx_;                                  \
      t1 = dX ? 1.0f - wx_ : wx_;                                         \
      t2 = dX ? wx_        : 0.0f; }

// One thread per (pixel, color); coordinates mirror make_filters(f64)+_warp(f32)
// (validated R2-R5). R6: back to acc[25] (R4's M[45] blew the register budget:
// VGPR_Count=64 < live set => spill, the real cause of R4/R5's 80 us), 3-buffer
// hand-pipelined rank loads, launch_bounds(192,2) so regalloc never spills.
// Keep R5's XCD row-band swizzle (FETCH 147->49 MB).
__global__ __launch_bounds__(BLK, 2) void multilayer_acc(
    const float* __restrict__ layers, float* __restrict__ out)
{
    const int lane = threadIdx.x & 63;
    const int c    = threadIdx.x >> 6;                         // wave-uniform
    const int cu   = __builtin_amdgcn_readfirstlane(c);        // → SGPR
    // XCD swizzle: round-robin dispatch => XCD k gets contiguous rows [48k,48k+48)
    const int b    = (blockIdx.x & 7) * 288 + (blockIdx.x >> 3);
    const int i    = b / 6;                                    // row
    const int j    = (b - i * 6) * 64 + lane;                  // col

    const double stepd = 2.0 / 383.0;            // np.linspace(-1,1,384) step
    const double flowx = (double)j * stepd - 1.0;
    const double flowy = (double)i * stepd - 1.0;

    // ---- x-axis tap tables (per-lane, VGPR) ----
    float ax0[5][3], ax1[3];
#pragma unroll
    for (int v = 0; v < 5; ++v) {
        const double d = ((-1.0 / 384.0) * (double)(v - 2)) * (-1.0);
        const float  g = (float)(d + flowx);
        MKTAP(g, j, ax0[v][0], ax0[v][1], ax0[v][2])
    }
    { const float g = (float)flowx; MKTAP(g, j, ax1[0], ax1[1], ax1[2]) }

    // ---- y-axis tap tables (block-uniform → SGPR) ----
    float ay0[5][3], ay1[3];
#pragma unroll
    for (int v = 0; v < 5; ++v) {
        const double d = ((-1.0 / 384.0) * (double)(v - 2)) * (-1.0);
        const float  g = (float)(d + flowy);
        float t0, t1, t2;
        MKTAP(g, i, t0, t1, t2)
        ay0[v][0] = uread(t0); ay0[v][1] = uread(t1); ay0[v][2] = uread(t2);
    }
    {
        const float g = (float)flowy;
        float t0, t1, t2;
        MKTAP(g, i, t0, t1, t2)
        // fold the 0.25 rank-mean into the middle-layer y-taps
        ay1[0] = uread(0.25f * t0); ay1[1] = uread(0.25f * t1); ay1[2] = uread(0.25f * t2);
    }

    // ---- 3x3 neighborhood byte offsets (clamped) ----
    const int jm = max(j - 1, 0), jp = min(j + 1, W - 1);
    const int im = max(i - 1, 0), ip = min(i + 1, H - 1);
    const int r0 = im * W, r1 = i * W, r2 = ip * W;
    const int voff[9] = { (r0 + jm) * 4, (r0 + j) * 4, (r0 + jp) * 4,
                          (r1 + jm) * 4, (r1 + j) * 4, (r1 + jp) * 4,
                          (r2 + jm) * 4, (r2 + j) * 4, (r2 + jp) * 4 };

    const char* base = (const char*)layers + (size_t)cu * (HW * 4);

    float acc[25];
#pragma unroll
    for (int a = 0; a < 25; ++a) acc[a] = 0.0f;

    // rank r, layer planes: ch = r*3 + cu (+0/12/24 planes for layers 0/1/2)
#define LOADR(r_, N0, N1, N2)                                             \
    { const char* p_ = base + (size_t)(r_) * (3 * HW * 4);                \
      _Pragma("unroll")                                                   \
      for (int t = 0; t < 9; ++t) {                                       \
          N0[t] = *(const float*)(p_ + voff[t]);                          \
          N1[t] = *(const float*)(p_ + (size_t)(12 * HW * 4) + voff[t]);  \
          N2[t] = *(const float*)(p_ + (size_t)(24 * HW * 4) + voff[t]);  \
      } }

#define COMPR(N0, N1, N2)                                                 \
    { float hy0 = ax1[0]*N1[0] + ax1[1]*N1[1] + ax1[2]*N1[2];             \
      float hy1 = ax1[0]*N1[3] + ax1[1]*N1[4] + ax1[2]*N1[5];             \
      float hy2 = ax1[0]*N1[6] + ax1[1]*N1[7] + ax1[2]*N1[8];             \
      const float v1 = ay1[0]*hy0 + ay1[1]*hy1 + ay1[2]*hy2;              \
      _Pragma("unroll")                                                   \
      for (int al = 0; al < 5; ++al) {                                    \
          float h0[3], h2[3];                                             \
          _Pragma("unroll")                                               \
          for (int dy = 0; dy < 3; ++dy) {                                \
              h0[dy] = (ax0[al][0]*N0[dy*3] + ax0[al][1]*N0[dy*3+1]       \
                        + ax0[al][2]*N0[dy*3+2]) * v1;                    \
              h2[dy] =  ax0[4-al][0]*N2[dy*3] + ax0[4-al][1]*N2[dy*3+1]   \
                        + ax0[4-al][2]*N2[dy*3+2];                        \
          }                                                               \
          _Pragma("unroll")                                               \
          for (int ak = 0; ak < 5; ++ak) {                                \
              const float s0 = ay0[ak][0]*h0[0] + ay0[ak][1]*h0[1]        \
                               + ay0[ak][2]*h0[2];                        \
              const float s2 = ay0[4-ak][0]*h2[0] + ay0[4-ak][1]*h2[1]    \
                               + ay0[4-ak][2]*h2[2];                      \
              acc[ak*5+al] = fmaf(s0, s2, acc[ak*5+al]);                  \
          } } }

    // hand-unrolled pipeline, 3 named buffers (no dynamic index => no scratch):
    // ranks 0..2 load up front (81 loads in flight), rank 3 prefetches under
    // rank 0's compute.
    float Xa[9], Ya[9], Za[9], Xb[9], Yb[9], Zb[9], Xc[9], Yc[9], Zc[9];
    LOADR(0, Xa, Ya, Za)
    LOADR(1, Xb, Yb, Zb)
    LOADR(2, Xc, Yc, Zc)
    COMPR(Xa, Ya, Za)
    LOADR(3, Xa, Ya, Za)
    COMPR(Xb, Yb, Zb)
    COMPR(Xc, Yc, Zc)
    COMPR(Xa, Ya, Za)
#undef LOADR
#undef COMPR

    // ---- 25 NT stores: out[a][c][i][j], a = ak*5+al (0.25 already folded) ----
    const size_t ob = (size_t)cu * HW + (size_t)i * W + j;
#pragma unroll
    for (int ak = 0; ak < 5; ++ak)
#pragma unroll
        for (int al = 0; al < 5; ++al)
            __builtin_nontemporal_store(acc[ak * 5 + al],
                out + (size_t)(ak * 5 + al) * (3 * HW) + ob);
}

extern "C" void kernel_launch(void* const* d_in, const int* in_sizes, int n_in,
                              void* d_out, int out_size, void* d_ws, size_t ws_size,
                              hipStream_t stream) {
    const float* layers = (const float*)d_in[0];   // [1,3,4,3,384,384] f32
    // d_in[1] (filters) unused: coordinates recomputed analytically (validated R2-R5).
    float* out = (float*)d_out;                    // [1,25,3,384,384] f32

    const int n_blocks = HW / 64;                  // 2304 blocks of 192 threads
    multilayer_acc<<<n_blocks, BLK, 0, stream>>>(layers, out);
}

// Round 7
// 149.574 us; speedup vs baseline: 1.3841x; 1.0083x over previous
//
#include <hip/hip_runtime.h>

#define H   384
#define W   384
#define HW  (H*W)
#define BLK 192   // 3 waves: one per output color channel

// Broadcast a wave-uniform float into an SGPR.
__device__ __forceinline__ float uread(float x) {
    return __int_as_float(__builtin_amdgcn_readfirstlane(__float_as_int(x)));
}

// 3-tap weights for one axis: the sample lands in [pos-1, pos+1]; fold the
// floor offset (0/1) into the taps so the hot loop is pure FMA.
#define MKTAP(g_, pos_, t0, t1, t2)                                       \
    { float x_  = fminf(fmaxf(((g_) + 1.0f) * 0.5f * 383.0f, 0.0f), 383.0f); \
      float x0f = floorf(x_);                                             \
      float wx_ = x_ - x0f;                                               \
      int   dX  = (int)x0f - (pos_) + 1;                                  \
      t0 = dX ? 0.0f       : 1.0f - wx_;                                  \
      t1 = dX ? 1.0f - wx_ : wx_;                                         \
      t2 = dX ? wx_        : 0.0f; }

// One thread per (pixel, color); coordinates mirror make_filters(f64)+_warp(f32)
// (validated R2-R6). R7 = R6's no-spill pipeline + R4's M-factorization:
//   M[al] = sum_r (h0*v1) h2^T   (9 FMA/al/rank instead of 35)
//   out[ak,al] = ay[ak]^T M[al] ay[4-ak]   (evaluated once, not per rank)
// R4/R5's 80us was NOT the M-scheme: launch_bounds(192,4) forced VGPR=64 onto
// a ~150-reg live set -> spill (WRITE 98.5 vs 44 MB ideal). (192,2) fixes it.
// Keep R5's XCD row-band swizzle (FETCH 147->49 MB) and NT stores.
__global__ __launch_bounds__(BLK, 2) void multilayer_m2(
    const float* __restrict__ layers, float* __restrict__ out)
{
    const int lane = threadIdx.x & 63;
    const int c    = threadIdx.x >> 6;                         // wave-uniform
    const int cu   = __builtin_amdgcn_readfirstlane(c);        // → SGPR
    // XCD swizzle: round-robin dispatch => XCD k gets contiguous rows [48k,48k+48)
    const int b    = (blockIdx.x & 7) * 288 + (blockIdx.x >> 3);
    const int i    = b / 6;                                    // row
    const int j    = (b - i * 6) * 64 + lane;                  // col

    const double stepd = 2.0 / 383.0;            // np.linspace(-1,1,384) step
    const double flowx = (double)j * stepd - 1.0;
    const double flowy = (double)i * stepd - 1.0;

    // ---- x-axis tap tables (per-lane, VGPR) ----
    float ax0[5][3], ax1[3];
#pragma unroll
    for (int v = 0; v < 5; ++v) {
        const double d = ((-1.0 / 384.0) * (double)(v - 2)) * (-1.0);
        const float  g = (float)(d + flowx);
        MKTAP(g, j, ax0[v][0], ax0[v][1], ax0[v][2])
    }
    { const float g = (float)flowx; MKTAP(g, j, ax1[0], ax1[1], ax1[2]) }

    // ---- y-axis tap tables (block-uniform → SGPR) ----
    float ay0[5][3], ay1[3];
#pragma unroll
    for (int v = 0; v < 5; ++v) {
        const double d = ((-1.0 / 384.0) * (double)(v - 2)) * (-1.0);
        const float  g = (float)(d + flowy);
        float t0, t1, t2;
        MKTAP(g, i, t0, t1, t2)
        ay0[v][0] = uread(t0); ay0[v][1] = uread(t1); ay0[v][2] = uread(t2);
    }
    {
        const float g = (float)flowy;
        float t0, t1, t2;
        MKTAP(g, i, t0, t1, t2)
        // fold the 0.25 rank-mean into the middle-layer y-taps
        ay1[0] = uread(0.25f * t0); ay1[1] = uread(0.25f * t1); ay1[2] = uread(0.25f * t2);
    }

    // ---- 3x3 neighborhood byte offsets (clamped) ----
    const int jm = max(j - 1, 0), jp = min(j + 1, W - 1);
    const int im = max(i - 1, 0), ip = min(i + 1, H - 1);
    const int r0 = im * W, r1 = i * W, r2 = ip * W;
    const int voff[9] = { (r0 + jm) * 4, (r0 + j) * 4, (r0 + jp) * 4,
                          (r1 + jm) * 4, (r1 + j) * 4, (r1 + jp) * 4,
                          (r2 + jm) * 4, (r2 + j) * 4, (r2 + jp) * 4 };

    const char* base = (const char*)layers + (size_t)cu * (HW * 4);

    float M[5][3][3] = {};   // M[al][p][q], accumulated across ranks

    // rank r planes: ch = r*3 + cu (+0/12/24 planes for layers 0/1/2)
#define LOADR(r_, N0, N1, N2)                                             \
    { const char* p_ = base + (size_t)(r_) * (3 * HW * 4);                \
      _Pragma("unroll")                                                   \
      for (int t = 0; t < 9; ++t) {                                       \
          N0[t] = *(const float*)(p_ + voff[t]);                          \
          N1[t] = *(const float*)(p_ + (size_t)(12 * HW * 4) + voff[t]);  \
          N2[t] = *(const float*)(p_ + (size_t)(24 * HW * 4) + voff[t]);  \
      } }

#define COMPM(N0, N1, N2)                                                 \
    { float hy0 = ax1[0]*N1[0] + ax1[1]*N1[1] + ax1[2]*N1[2];             \
      float hy1 = ax1[0]*N1[3] + ax1[1]*N1[4] + ax1[2]*N1[5];             \
      float hy2 = ax1[0]*N1[6] + ax1[1]*N1[7] + ax1[2]*N1[8];             \
      const float v1 = ay1[0]*hy0 + ay1[1]*hy1 + ay1[2]*hy2;              \
      _Pragma("unroll")                                                   \
      for (int al = 0; al < 5; ++al) {                                    \
          float h0[3], h2[3];                                             \
          _Pragma("unroll")                                               \
          for (int dy = 0; dy < 3; ++dy) {                                \
              h0[dy] = (ax0[al][0]*N0[dy*3] + ax0[al][1]*N0[dy*3+1]       \
                        + ax0[al][2]*N0[dy*3+2]) * v1;                    \
              h2[dy] =  ax0[4-al][0]*N2[dy*3] + ax0[4-al][1]*N2[dy*3+1]   \
                        + ax0[4-al][2]*N2[dy*3+2];                        \
          }                                                               \
          _Pragma("unroll")                                               \
          for (int p = 0; p < 3; ++p)                                     \
              _Pragma("unroll")                                           \
              for (int q = 0; q < 3; ++q)                                 \
                  M[al][p][q] = fmaf(h0[p], h2[q], M[al][p][q]);          \
      } }

    // 2-buffer hand pipeline (named arrays, no dynamic index => no scratch)
    float Xa[9], Ya[9], Za[9], Xb[9], Yb[9], Zb[9];
    LOADR(0, Xa, Ya, Za)
    LOADR(1, Xb, Yb, Zb)
    COMPM(Xa, Ya, Za)
    LOADR(2, Xa, Ya, Za)
    COMPM(Xb, Yb, Zb)
    LOADR(3, Xb, Yb, Zb)
    COMPM(Xa, Ya, Za)
    COMPM(Xb, Yb, Zb)
#undef LOADR
#undef COMPM

    // ---- 25 quadratic forms, one NT store each: out[a][c][i][j], a = ak*5+al ----
    const size_t ob = (size_t)cu * HW + (size_t)i * W + j;
#pragma unroll
    for (int ak = 0; ak < 5; ++ak) {
        const float q0 = ay0[4 - ak][0], q1 = ay0[4 - ak][1], q2 = ay0[4 - ak][2];
        const float l0 = ay0[ak][0],     l1 = ay0[ak][1],     l2 = ay0[ak][2];
#pragma unroll
        for (int al = 0; al < 5; ++al) {
            const float t0 = M[al][0][0] * q0 + M[al][0][1] * q1 + M[al][0][2] * q2;
            const float t1 = M[al][1][0] * q0 + M[al][1][1] * q1 + M[al][1][2] * q2;
            const float t2 = M[al][2][0] * q0 + M[al][2][1] * q1 + M[al][2][2] * q2;
            const float s  = l0 * t0 + l1 * t1 + l2 * t2;
            __builtin_nontemporal_store(s, out + (size_t)(ak * 5 + al) * (3 * HW) + ob);
        }
    }
}

extern "C" void kernel_launch(void* const* d_in, const int* in_sizes, int n_in,
                              void* d_out, int out_size, void* d_ws, size_t ws_size,
                              hipStream_t stream) {
    const float* layers = (const float*)d_in[0];   // [1,3,4,3,384,384] f32
    // d_in[1] (filters) unused: coordinates recomputed analytically (validated R2-R6).
    float* out = (float*)d_out;                    // [1,25,3,384,384] f32

    const int n_blocks = HW / 64;                  // 2304 blocks of 192 threads
    multilayer_m2<<<n_blocks, BLK, 0, stream>>>(layers, out);
}